// Round 17
// baseline (269.571 us; speedup 1.0000x reference)
//
#include <hip/hip_runtime.h>
#include <hip/hip_bf16.h>

// B=2, S=2048, HID=2048, NH=16, HD=128.
// r16 config + 256x256 QKV GEMM (single-barrier, 2-buffer depth-1 with
// early-staged tiles: 64 MFMA/wave per barrier, full-tile MFMA cover for the
// boundary drain). Proj keeps the r16 256x128 3-buffer kernel. Attn verbatim.

typedef __attribute__((ext_vector_type(8))) short short8_t;   // 8 x bf16
typedef __attribute__((ext_vector_type(4))) short short4_t;
typedef __attribute__((ext_vector_type(4))) float f32x4;

#define S_LEN 2048
#define NHEAD 16
#define HDIM  128
#define HID   2048
#define MROWS 4096            // B*S
#define SCALEF 0.08838834764831845f

__device__ __forceinline__ float bf2f(ushort u) {
  union { unsigned int u; float f; } a; a.u = ((unsigned int)u) << 16; return a.f;
}
__device__ __forceinline__ ushort f2bf(float f) {
  union { float f; unsigned int u; } a; a.f = f;
  unsigned int r = a.u + 0x7FFFu + ((a.u >> 16) & 1u);
  return (ushort)(r >> 16);
}
__device__ __forceinline__ void store_out(ushort* p, float v) { *p = f2bf(v); }
__device__ __forceinline__ void store_out(float* p, float v) { *p = v; }

// async global->LDS, 16B per lane; LDS dest must be wave-uniform (HW adds lane*16).
__device__ __forceinline__ void gload_lds16(const void* g, void* l) {
  __builtin_amdgcn_global_load_lds(
      (const __attribute__((address_space(1))) unsigned int*)g,
      (__attribute__((address_space(3))) unsigned int*)l, 16, 0, 0);
}

// ---------------------------------------------------------------- fused casts
__global__ __launch_bounds__(256) void cast_all_kernel(
    const float* __restrict__ x, const float* __restrict__ wq,
    const float* __restrict__ wk, const float* __restrict__ wv,
    const float* __restrict__ wo, ushort* __restrict__ xb,
    ushort* __restrict__ wqkvb, ushort* __restrict__ wob) {
  int i = blockIdx.x * 256 + threadIdx.x;
  const int stride = gridDim.x * 256;
  for (; i < 6291456; i += stride) {
    const float4* src; short4_t* dst; int off;
    if (i < 2097152)      { src = (const float4*)x;  dst = (short4_t*)xb;               off = i; }
    else if (i < 3145728) { src = (const float4*)wq; dst = (short4_t*)wqkvb;            off = i - 2097152; }
    else if (i < 4194304) { src = (const float4*)wk; dst = (short4_t*)wqkvb + 1048576;  off = i - 3145728; }
    else if (i < 5242880) { src = (const float4*)wv; dst = (short4_t*)wqkvb + 2097152;  off = i - 4194304; }
    else                  { src = (const float4*)wo; dst = (short4_t*)wob;              off = i - 5242880; }
    float4 v = src[off];
    short4_t o = { (short)f2bf(v.x), (short)f2bf(v.y),
                   (short)f2bf(v.z), (short)f2bf(v.w) };
    dst[off] = o;
  }
}

// ---------------------------------------------------------------- rope tables
__global__ __launch_bounds__(256) void rope_tab_kernel(
    float* __restrict__ cosT, float* __restrict__ sinT) {
  int idx = blockIdx.x * 256 + threadIdx.x;
  if (idx >= S_LEN * 64) return;
  int s = idx >> 6, i = idx & 63;
  float f = expf(9.2103403719761836f * (float)(2 * i));
  float inv = 1.0f / f;                 // inf -> 0, matches reference
  float ang = (float)s * inv;
  cosT[idx] = cosf(ang);
  sinT[idx] = sinf(ang);
}

// ---------------------------------------------------------------- QKV GEMM 256x256
// BM=BN=256, BK=64. 8 waves (2m x 4n), per-wave C = 128x64 (acc[8][4]).
// LDS: 2 buffers x (A [256][64] 32KB + B [256][64] 32KB) = 128 KB.
// Swizzle: byte = row*128 + ((chunk ^ (row&7))<<4); global src pre-swizzled.
// Loop: stage ALL of tile T+1 (8 calls) first -> 64 MFMA cover (~2500 cyc/SIMD)
// -> vmcnt(0) (T+1 landed) -> barrier. Stages hit buf p^1 whose reads finished
// last iteration (barrier-separated) -> no hazard.
// z<2 -> fused RoPE+RMSNorm epilogue, run in two 128-col (per-head) passes.
__global__ __launch_bounds__(512, 2) void gemm256_kernel(
    const ushort* __restrict__ A, const ushort* __restrict__ W,
    ushort* __restrict__ C, int M, int N, int K,
    const float* __restrict__ qnw, const float* __restrict__ knw,
    const float* __restrict__ cosT, const float* __restrict__ sinT) {
  __shared__ __align__(16) char lds[131072];    // 2 x (A 32KB + B 32KB)

  const int n0 = blockIdx.x * 256;
  const int m0 = blockIdx.y * 256;
  const ushort* Wz = W + (size_t)blockIdx.z * N * K;
  ushort* Cz = C + (size_t)blockIdx.z * M * N;

  const int tid = threadIdx.x;
  const int lane = tid & 63, wid = tid >> 6;
  const int lq = lane & 15, lg = lane >> 4;
  const int wm = wid >> 2, wn = wid & 3;        // 2m x 4n
  const int NT = K >> 6;                        // BK = 64
  const int wb = wid * 1024;                    // wave-uniform base per call

  const int strow = tid >> 3;                   // 0..63
  const int sc8 = (((tid & 7) ^ (strow & 7)) << 3);
  const ushort* pa = A + (size_t)(m0 + strow) * K + sc8;
  const ushort* pw = Wz + (size_t)(n0 + strow) * K + sc8;

  // stage tile into buf BI (8 calls: A rows 0..255, B rows 0..255)
#define STG256(BI, KC) { \
    _Pragma("unroll") for (int c = 0; c < 4; ++c) \
      gload_lds16(pa + (size_t)(c * 64) * K + (KC), lds + (BI) * 65536 + c * 8192 + wb); \
    _Pragma("unroll") for (int c = 0; c < 4; ++c) \
      gload_lds16(pw + (size_t)(c * 64) * K + (KC), lds + (BI) * 65536 + 32768 + c * 8192 + wb); }

  f32x4 acc[8][4];
#pragma unroll
  for (int i = 0; i < 8; i++)
#pragma unroll
    for (int j = 0; j < 4; j++) acc[i][j] = (f32x4){0.f, 0.f, 0.f, 0.f};

  STG256(0, 0);
  asm volatile("s_waitcnt vmcnt(0)" ::: "memory");
  __builtin_amdgcn_s_barrier();
  __builtin_amdgcn_sched_barrier(0);

  for (int t = 0; t < NT; ++t) {
    const char* bufp = lds + (t & 1) * 65536;
    const bool st = (t + 1 < NT);
    if (st) STG256((t + 1) & 1, (t + 1) << 6);

    short8_t af[8], bfr[4];
#pragma unroll
    for (int kk = 0; kk < 2; ++kk) {
#pragma unroll
      for (int j = 0; j < 4; ++j) {
        const int rw = wn * 64 + j * 16 + lq;
        bfr[j] = *(const short8_t*)(bufp + 32768 + rw * 128 +
                                    (((kk * 4 + lg) ^ (rw & 7)) << 4));
      }
#pragma unroll
      for (int i = 0; i < 8; ++i) {
        const int rw = wm * 128 + i * 16 + lq;
        af[i] = *(const short8_t*)(bufp + rw * 128 +
                                   (((kk * 4 + lg) ^ (rw & 7)) << 4));
      }
      asm volatile("s_waitcnt lgkmcnt(0)" ::: "memory");
      __builtin_amdgcn_sched_barrier(0);
      __builtin_amdgcn_s_setprio(1);
#pragma unroll
      for (int i = 0; i < 8; ++i)
#pragma unroll
        for (int j = 0; j < 4; ++j)
          acc[i][j] = __builtin_amdgcn_mfma_f32_16x16x32_bf16(
              af[i], bfr[j], acc[i][j], 0, 0, 0);
      __builtin_amdgcn_s_setprio(0);
    }

    if (st) asm volatile("s_waitcnt vmcnt(0)" ::: "memory");
    __builtin_amdgcn_s_barrier();
    __builtin_amdgcn_sched_barrier(0);
  }

  if (blockIdx.z < 2) {
    // ---- fused RoPE + RMSNorm epilogue, two per-head passes (cols 0-127,128-255)
    const float* nw = (blockIdx.z == 0) ? qnw : knw;
    const float oscale = (blockIdx.z == 0) ? 0.12753102368f : 1.0f;  // CL2 fold
    ushort* CT = (ushort*)lds;                  // [256][136] bf16 = 69.6 KB
#pragma unroll
    for (int ph = 0; ph < 2; ++ph) {
      if ((wn >> 1) == ph) {                    // waves owning these 128 cols
#pragma unroll
        for (int mi = 0; mi < 8; mi++)
#pragma unroll
          for (int r = 0; r < 4; r++) {
            const int row = wm * 128 + mi * 16 + lg * 4 + r;
#pragma unroll
            for (int j = 0; j < 4; j++)
              CT[row * 136 + (wn & 1) * 64 + j * 16 + lq] = f2bf(acc[mi][j][r]);
          }
      }
      __syncthreads();
      {
        const int row = tid >> 1;
        const int i0 = (tid & 1) * 32;
        const int m = m0 + row;
        const int s = m & (S_LEN - 1);
        float y1[32], y2[32];
        float ss = 0.f;
#pragma unroll
        for (int q8 = 0; q8 < 8; ++q8) {
          const float4 c4 = *(const float4*)&cosT[s * 64 + i0 + q8 * 4];
          const float4 s4 = *(const float4*)&sinT[s * 64 + i0 + q8 * 4];
          const short4_t x1v = *(const short4_t*)&CT[row * 136 + i0 + q8 * 4];
          const short4_t x2v = *(const short4_t*)&CT[row * 136 + 64 + i0 + q8 * 4];
#pragma unroll
          for (int e = 0; e < 4; ++e) {
            const float c = (&c4.x)[e], sn = (&s4.x)[e];
            const float x1 = bf2f((ushort)x1v[e]);
            const float x2 = bf2f((ushort)x2v[e]);
            const int k = q8 * 4 + e;
            y1[k] = x1 * c - x2 * sn;
            y2[k] = x2 * c + x1 * sn;
            ss += y1[k] * y1[k] + y2[k] * y2[k];
          }
        }
        ss += __shfl_xor(ss, 1, 64);
        const float sc = rsqrtf(ss * (1.f / 128.f) + 1e-6f) * oscale;
        ushort* gp = Cz + (size_t)m * N + n0 + ph * 128;
#pragma unroll
        for (int cu = 0; cu < 4; ++cu) {
          const float4 wa0 = *(const float4*)&nw[i0 + cu * 8];
          const float4 wa1 = *(const float4*)&nw[i0 + cu * 8 + 4];
          const float4 wb0 = *(const float4*)&nw[i0 + 64 + cu * 8];
          const float4 wb1 = *(const float4*)&nw[i0 + 64 + cu * 8 + 4];
          short8_t o1, o2;
#pragma unroll
          for (int e = 0; e < 8; ++e) {
            const int k = cu * 8 + e;
            const float w1 = (e < 4) ? (&wa0.x)[e] : (&wa1.x)[e - 4];
            const float w2 = (e < 4) ? (&wb0.x)[e] : (&wb1.x)[e - 4];
            o1[e] = (short)f2bf(y1[k] * sc * w1);
            o2[e] = (short)f2bf(y2[k] * sc * w2);
          }
          *(short8_t*)&gp[i0 + cu * 8] = o1;
          *(short8_t*)&gp[i0 + 64 + cu * 8] = o2;
        }
      }
      __syncthreads();                          // CT reused by next pass
    }
    return;
  }

  // plain bf16 write (v slab, z == 2)
#pragma unroll
  for (int mi = 0; mi < 8; mi++) {
#pragma unroll
    for (int r = 0; r < 4; r++) {
      const int m = m0 + wm * 128 + mi * 16 + lg * 4 + r;
      ushort* cp = Cz + (size_t)m * N + n0 + wn * 64 + lq;
#pragma unroll
      for (int j = 0; j < 4; j++) cp[j * 16] = f2bf(acc[mi][j][r]);
    }
  }
}

// ---------------------------------------------------------------- proj GEMM
// r16 kernel verbatim (BM256xBN128xBK64, 3-buffer depth-2, single-barrier,
// XCD-rectangular swizzle). fp32 out.
__global__ __launch_bounds__(512, 2) void gemm_pipe_kernel(
    const ushort* __restrict__ A, const ushort* __restrict__ W,
    float* __restrict__ C, int M, int N, int K) {
  constexpr int ABYTES = 32768;
  constexpr int BUF = 49152;
  __shared__ __align__(16) char lds[3 * BUF];

  const int flat = blockIdx.y * 16 + blockIdx.x;
  const int xc = flat & 7, xr = flat >> 3;
  const int n0 = ((xc & 3) * 4 + (xr & 3)) * 128;
  const int m0 = ((xc >> 2) * 8 + (xr >> 2)) * 256;

  const int tid = threadIdx.x;
  const int lane = tid & 63, wid = tid >> 6;
  const int lq = lane & 15, lg = lane >> 4;
  const int wm = wid >> 1, wn = wid & 1;
  const int NT = K >> 6;
  const int wb = wid * 1024;

  const int strow = tid >> 3;
  const int sc8 = (((tid & 7) ^ (strow & 7)) << 3);
  const ushort* pa = A + (size_t)(m0 + strow) * K + sc8;
  const ushort* pw = W + (size_t)(n0 + strow) * K + sc8;

#define STG_P0(BI, KC) { \
    gload_lds16(pa + (KC), lds + (BI) * BUF + wb); \
    gload_lds16(pa + (size_t)64 * K + (KC), lds + (BI) * BUF + 8192 + wb); \
    gload_lds16(pw + (KC), lds + (BI) * BUF + ABYTES + wb); }
#define STG_P1(BI, KC) { \
    gload_lds16(pa + (size_t)128 * K + (KC), lds + (BI) * BUF + 16384 + wb); \
    gload_lds16(pa + (size_t)192 * K + (KC), lds + (BI) * BUF + 24576 + wb); \
    gload_lds16(pw + (size_t)64 * K + (KC), lds + (BI) * BUF + ABYTES + 8192 + wb); }

  f32x4 acc[4][4];
#pragma unroll
  for (int i = 0; i < 4; i++)
#pragma unroll
    for (int j = 0; j < 4; j++) acc[i][j] = (f32x4){0.f, 0.f, 0.f, 0.f};

  STG_P0(0, 0); STG_P1(0, 0);
  STG_P0(1, 64); STG_P1(1, 64);
  asm volatile("s_waitcnt vmcnt(6)" ::: "memory");
  __builtin_amdgcn_s_barrier();
  __builtin_amdgcn_sched_barrier(0);

  int b = 0, b2 = 2;
  for (int t = 0; t < NT; ++t) {
    const int kc2 = (t + 2) << 6;
    const bool st = (t + 2 < NT);
    const char* bufp = lds + b * BUF;
    short8_t af[2][4], bfr[2][4];

#pragma unroll
    for (int kk = 0; kk < 2; ++kk) {
#pragma unroll
      for (int j = 0; j < 4; ++j) {
        const int rw = wn * 64 + j * 16 + lq;
        bfr[kk][j] = *(const short8_t*)(bufp + ABYTES + rw * 128 +
                                        (((kk * 4 + lg) ^ (rw & 7)) << 4));
      }
#pragma unroll
      for (int i = 0; i < 4; ++i) {
        const int rw = wm * 64 + i * 16 + lq;
        af[kk][i] = *(const short8_t*)(bufp + rw * 128 +
                                       (((kk * 4 + lg) ^ (rw & 7)) << 4));
      }
    }
    if (st) { STG_P0(b2, kc2); STG_P1(b2, kc2); }

    asm volatile("s_waitcnt lgkmcnt(0)" ::: "memory");
    __builtin_amdgcn_sched_barrier(0);
    __builtin_amdgcn_s_setprio(1);
#pragma unroll
    for (int kk = 0; kk < 2; ++kk)
#pragma unroll
      for (int i = 0; i < 4; ++i)
#pragma unroll
        for (int j = 0; j < 4; ++j)
          acc[i][j] = __builtin_amdgcn_mfma_f32_16x16x32_bf16(
              af[kk][i], bfr[kk][j], acc[i][j], 0, 0, 0);
    __builtin_amdgcn_s_setprio(0);

    if (st) asm volatile("s_waitcnt vmcnt(6)" ::: "memory");
    else    asm volatile("s_waitcnt vmcnt(0)" ::: "memory");
    __builtin_amdgcn_s_barrier();
    __builtin_amdgcn_sched_barrier(0);
    b = (b == 2) ? 0 : b + 1;
    b2 = (b2 == 2) ? 0 : b2 + 1;
  }

#pragma unroll
  for (int mi = 0; mi < 4; mi++) {
#pragma unroll
    for (int r = 0; r < 4; r++) {
      const int m = m0 + wm * 64 + mi * 16 + lg * 4 + r;
      float* cp = C + (size_t)m * N + n0 + wn * 64 + lq;
#pragma unroll
      for (int j = 0; j < 4; j++) cp[j * 16] = acc[mi][j][r];
    }
  }
}

// ---------------------------------------------------------------- flash attention
// ROUND-9 KERNEL VERBATIM (fixed-shift exp2 softmax, XCD-grouped heads).
__global__ __launch_bounds__(256) void attn_kernel(
    const ushort* __restrict__ Q, const ushort* __restrict__ K,
    const ushort* __restrict__ V, ushort* __restrict__ O) {
  __shared__ __align__(16) char LB[2][34816];

  const int bid = blockIdx.x;
  const int xcd = bid & 7;
  const int rr  = bid >> 3;
  const int bh  = xcd * 4 + (rr >> 4);
  const int jj  = rr & 15;
  const int h = bh & 15, b = bh >> 4;
  const int tid = threadIdx.x;
  const int lane = tid & 63, w = tid >> 6;
  const int lq = lane & 15, lg = lane >> 4;

  const int vp  = tid & 15;
  const int vd0 = (tid >> 4) * 8;
  const int vc  = (vp < 8) ? ((vp >> 1) * 4 + (vp & 1))
                           : (((vp - 8) >> 1) * 4 + 2 + (vp & 1));
  const size_t bS = (size_t)b * S_LEN;

  union S8U4 { short8_t s; uint u[4]; };

#define STAGE_K64(DST, KBASE) _Pragma("unroll") for (int c = 0; c < 4; ++c) { \
    const int kr = w * 16 + c * 4 + (lane >> 4); \
    const int kc = ((lane & 15) * 16) ^ ((kr & 7) << 4); \
    gload_lds16(K + (KBASE) + (size_t)kr * HID + (kc >> 1), (DST) + w * 4096 + c * 1024); }

#define STAGE_V_LOAD(KBASE) { \
    const ushort* vs = V + (KBASE) + (size_t)(2 * vp) * HID + vd0; \
    va0.s = *(const short8_t*)vs;            vb0.s = *(const short8_t*)(vs + HID); \
    va1.s = *(const short8_t*)(vs + 32 * HID); vb1.s = *(const short8_t*)(vs + 33 * HID); }

#define STAGE_V_WRITE(VT0, VT1) \
    _Pragma("unroll") for (int j = 0; j < 4; ++j) { \
      (VT0)[(vd0 + 2 * j) * 18 + vc]     = __builtin_amdgcn_perm(vb0.u[j], va0.u[j], 0x05040100u); \
      (VT0)[(vd0 + 2 * j + 1) * 18 + vc] = __builtin_amdgcn_perm(vb0.u[j], va0.u[j], 0x07060302u); \
      (VT1)[(vd0 + 2 * j) * 18 + vc]     = __builtin_amdgcn_perm(vb1.u[j], va1.u[j], 0x05040100u); \
      (VT1)[(vd0 + 2 * j + 1) * 18 + vc] = __builtin_amdgcn_perm(vb1.u[j], va1.u[j], 0x07060302u); }

  for (int t = 0; t < 2; t++) {
    const int qt = t ? (31 - jj) : jj;
    const int q0 = qt * 64 + w * 16;
    const int qg = q0 + lq;

    const ushort* qp = Q + (bS + q0 + lq) * HID + h * HDIM + lg * 8;
    short8_t qf[4];
#pragma unroll
    for (int dc = 0; dc < 4; dc++) qf[dc] = *(const short8_t*)(qp + dc * 32);

    f32x4 o[8];
#pragma unroll
    for (int i = 0; i < 8; i++) o[i] = (f32x4){0.f, 0.f, 0.f, 0.f};
    float l_run = 0.f;
    const int NI = qt + 1;

    {
      S8U4 va0, vb0, va1, vb1;
      uint* Vt0 = (uint*)(LB[0] + 16384);
      uint* Vt1 = (uint*)(LB[0] + 25600);
      const size_t kb0 = bS * HID + h * HDIM;
      STAGE_V_LOAD(kb0);
      STAGE_K64(LB[0], kb0);
      STAGE_V_WRITE(Vt0, Vt1);
    }
    __syncthreads();

    for (int i = 0; i < NI; ++i) {
      const int cur = i & 1;
      const int k0 = i * 64;
      const char* Ksb = LB[cur];
      const uint* Vt0 = (const uint*)(LB[cur] + 16384);
      const uint* Vt1 = (const uint*)(LB[cur] + 25600);
      char* KsbN = LB[cur ^ 1];
      uint* VtN0 = (uint*)(LB[cur ^ 1] + 16384);
      uint* VtN1 = (uint*)(LB[cur ^ 1] + 25600);
      const bool more = (i + 1 < NI);

      S8U4 va0, vb0, va1, vb1;
      if (more) {
        const size_t kbn = (bS + k0 + 64) * HID + h * HDIM;
        STAGE_V_LOAD(kbn);
        STAGE_K64(KsbN, kbn);
      }

      f32x4 st[4];
#pragma unroll
      for (int kb = 0; kb < 4; ++kb) st[kb] = (f32x4){0.f, 0.f, 0.f, 0.f};
      __builtin_amdgcn_s_setprio(1);
#pragma unroll
      for (int dc = 0; dc < 4; ++dc)
#pragma unroll
        for (int kb = 0; kb < 4; ++kb) {
          const int row = kb * 16 + lq;
          short8_t kf = *(const short8_t*)(Ksb + ((row * 256 + dc * 64 + lg * 16) ^ ((row & 7) << 4)));
          st[kb] = __builtin_amdgcn_mfma_f32_16x16x32_bf16(kf, qf[dc], st[kb], 0, 0, 0);
        }
      __builtin_amdgcn_s_setprio(0);

      if (more) STAGE_V_WRITE(VtN0, VtN1);

      float p[16]; float ps = 0.f;
#pragma unroll
      for (int kb = 0; kb < 4; ++kb)
#pragma unroll
        for (int r = 0; r < 4; ++r) {
          const int kk = k0 + kb * 16 + lg * 4 + r;
          const float e = exp2f((kk <= qg) ? st[kb][r] : -1e30f);
          p[kb * 4 + r] = e;
          ps += e;
        }
      l_run += ps;

      uint pk[8];
#pragma unroll
      for (int j = 0; j < 8; ++j)
        asm("v_cvt_pk_bf16_f32 %0, %1, %2" : "=v"(pk[j]) : "v"(p[2 * j]), "v"(p[2 * j + 1]));
      union { uint u[4]; short8_t s; } P0, P1;
      P0.u[0] = pk[0]; P0.u[1] = pk[1]; P0.u[2] = pk[2]; P0.u[3] = pk[3];
      P1.u[0] = pk[4]; P1.u[1] = pk[5]; P1.u[2] = pk[6]; P1.u[3] = pk[7];

      __builtin_amdgcn_s_setprio(1);
#pragma unroll
      for (int nt = 0; nt < 8; nt++) {
        const uint* vq0 = &Vt0[(nt * 16 + lq) * 18 + lg * 4];
        const uint* vq1 = &Vt1[(nt * 16 + lq) * 18 + lg * 4];
        uint2 a0 = *(const uint2*)vq0, a1 = *(const uint2*)(vq0 + 2);
        uint2 b0v = *(const uint2*)vq1, b1v = *(const uint2*)(vq1 + 2);
        union { uint u[4]; short8_t s; } V0, V1;
        V0.u[0] = a0.x; V0.u[1] = a0.y; V0.u[2] = a1.x; V0.u[3] = a1.y;
        V1.u[0] = b0v.x; V1.u[1] = b0v.y; V1.u[2] = b1v.x; V1.u[3] = b1v.y;
        o[nt] = __builtin_amdgcn_mfma_f32_16x16x32_bf16(P0.s, V0.s, o[nt], 0, 0, 0);
        o[nt] = __builtin_amdgcn_mfma_f32_16x16x32_bf16(P1.s, V1.s, o[nt], 0, 0, 0);
      }
      __builtin_amdgcn_s_setprio(0);

      __syncthreads();
    }

    float lf = l_run;
    lf += __shfl_xor(lf, 16, 64);
    lf += __shfl_xor(lf, 32, 64);
    const float invl = 1.f / lf;
#pragma unroll
    for (int r = 0; r < 4; r++) {
      const float iv = __shfl(invl, lg * 4 + r, 64);
      ushort* op = O + (bS + q0 + lg * 4 + r) * HID + h * HDIM + lq;
#pragma unroll
      for (int nt = 0; nt < 8; nt++) op[nt * 16] = f2bf(o[nt][r] * iv);
    }
    __syncthreads();
  }
}

// ---------------------------------------------------------------- launcher
extern "C" void kernel_launch(void* const* d_in, const int* in_sizes, int n_in,
                              void* d_out, int out_size, void* d_ws, size_t ws_size,
                              hipStream_t stream) {
  const float* x   = (const float*)d_in[0];
  const float* wq  = (const float*)d_in[1];
  const float* wk  = (const float*)d_in[2];
  const float* wv  = (const float*)d_in[3];
  const float* wo  = (const float*)d_in[4];
  const float* qnw = (const float*)d_in[5];
  const float* knw = (const float*)d_in[6];
  float* out = (float*)d_out;
  char* ws = (char*)d_ws;

  const size_t NELEM = (size_t)MROWS * HID;       // 8388608
  const size_t WELEM = (size_t)HID * HID;         // 4194304

  ushort* xb    = (ushort*)(ws);                          // 16777216 B
  ushort* wqkvb = (ushort*)(ws + 16777216);               // 25165824 B
  ushort* wob   = (ushort*)(ws + 41943040);               //  8388608 B
  ushort* qkv   = (ushort*)(ws + 50331648);               // 50331648 B (q,k,v)
  float*  cosT  = (float*)(ws + 100663296);               //   524288 B
  float*  sinT  = (float*)(ws + 101187584);               //   524288 B
  ushort* attnb = xb;                                     // alias (xb dead after QKV)

  cast_all_kernel<<<2048, 256, 0, stream>>>(x, wq, wk, wv, wo, xb, wqkvb, wob);
  rope_tab_kernel<<<512, 256, 0, stream>>>(cosT, sinT);

  // QKV: 256x256 tiles, fused rope+rmsnorm epilogue on q/k slabs
  gemm256_kernel<<<dim3(8, 16, 3), 512, 0, stream>>>(
      xb, wqkvb, qkv, MROWS, HID, HID, qnw, knw, cosT, sinT);

  // attention: 512 blocks x 256 threads, XCD-grouped heads, 64-key rounds
  attn_kernel<<<512, 256, 0, stream>>>(qkv, qkv + NELEM, qkv + 2 * NELEM, attnb);

  // out = attn @ wo^T (fp32 out): r16 256x128 kernel, swizzled
  gemm_pipe_kernel<<<dim3(16, 16, 1), 512, 0, stream>>>(
      attnb, wob, out, MROWS, HID, HID);
}

// Round 18
// 256.940 us; speedup vs baseline: 1.0492x; 1.0492x over previous
//
#include <hip/hip_runtime.h>
#include <hip/hip_bf16.h>

// B=2, S=2048, HID=2048, NH=16, HD=128.
// ROUND-16 CONFIG VERBATIM (measured best 258.8 us) + rope_tab folded into
// cast_all (saves one dispatch):
//  - fused cast->bf16 + rope tables (one kernel)
//  - QKV GEMM: BM256xBN128xBK64, 3-buffer depth-2 counted-vmcnt, single-barrier
//    K-loop (32 MFMA/barrier), XCD-rectangular swizzle, fused rope+rmsnorm
//    epilogue (q pre-scaled CL2)
//  - attention: round-9 kernel verbatim
//  - projection: same GEMM, fp32 out

typedef __attribute__((ext_vector_type(8))) short short8_t;   // 8 x bf16
typedef __attribute__((ext_vector_type(4))) short short4_t;
typedef __attribute__((ext_vector_type(4))) float f32x4;

#define S_LEN 2048
#define NHEAD 16
#define HDIM  128
#define HID   2048
#define MROWS 4096            // B*S
#define SCALEF 0.08838834764831845f

__device__ __forceinline__ float bf2f(ushort u) {
  union { unsigned int u; float f; } a; a.u = ((unsigned int)u) << 16; return a.f;
}
__device__ __forceinline__ ushort f2bf(float f) {
  union { float f; unsigned int u; } a; a.f = f;
  unsigned int r = a.u + 0x7FFFu + ((a.u >> 16) & 1u);
  return (ushort)(r >> 16);
}
__device__ __forceinline__ void store_out(ushort* p, float v) { *p = f2bf(v); }
__device__ __forceinline__ void store_out(float* p, float v) { *p = v; }

// async global->LDS, 16B per lane; LDS dest must be wave-uniform (HW adds lane*16).
__device__ __forceinline__ void gload_lds16(const void* g, void* l) {
  __builtin_amdgcn_global_load_lds(
      (const __attribute__((address_space(1))) unsigned int*)g,
      (__attribute__((address_space(3))) unsigned int*)l, 16, 0, 0);
}

// ---------------------------------------------------------------- fused casts + rope tables
__global__ __launch_bounds__(256) void cast_all_kernel(
    const float* __restrict__ x, const float* __restrict__ wq,
    const float* __restrict__ wk, const float* __restrict__ wv,
    const float* __restrict__ wo, ushort* __restrict__ xb,
    ushort* __restrict__ wqkvb, ushort* __restrict__ wob,
    float* __restrict__ cosT, float* __restrict__ sinT) {
  int i = blockIdx.x * 256 + threadIdx.x;
  const int stride = gridDim.x * 256;
  for (; i < 6422528; i += stride) {
    if (i < 6291456) {
      const float4* src; short4_t* dst; int off;
      if (i < 2097152)      { src = (const float4*)x;  dst = (short4_t*)xb;               off = i; }
      else if (i < 3145728) { src = (const float4*)wq; dst = (short4_t*)wqkvb;            off = i - 2097152; }
      else if (i < 4194304) { src = (const float4*)wk; dst = (short4_t*)wqkvb + 1048576;  off = i - 3145728; }
      else if (i < 5242880) { src = (const float4*)wv; dst = (short4_t*)wqkvb + 2097152;  off = i - 4194304; }
      else                  { src = (const float4*)wo; dst = (short4_t*)wob;              off = i - 5242880; }
      float4 v = src[off];
      short4_t o = { (short)f2bf(v.x), (short)f2bf(v.y),
                     (short)f2bf(v.z), (short)f2bf(v.w) };
      dst[off] = o;
    } else {
      // rope tables: idx in [0, S_LEN*64)
      const int idx = i - 6291456;
      const int s = idx >> 6, d = idx & 63;
      const float f = expf(9.2103403719761836f * (float)(2 * d));
      const float inv = 1.0f / f;           // inf -> 0, matches reference
      const float ang = (float)s * inv;
      cosT[idx] = cosf(ang);
      sinT[idx] = sinf(ang);
    }
  }
}

// ---------------------------------------------------------------- pipelined GEMM
// BM=256 x BN=128, BK=64, 3 buffers, depth-2 counted vmcnt, conflict-free XOR
// swizzle, XCD-rectangular grid swizzle, single-barrier K-loop (r16 winner).
#define MFMA_KK(KK) _Pragma("unroll") for (int i = 0; i < 4; ++i) \
    _Pragma("unroll") for (int j = 0; j < 4; ++j) \
      acc[i][j] = __builtin_amdgcn_mfma_f32_16x16x32_bf16( \
          af[KK][i], bfr[KK][j], acc[i][j], 0, 0, 0);

template <typename OutT, bool ROPE>
__global__ __launch_bounds__(512, 2) void gemm_pipe_kernel(
    const ushort* __restrict__ A, const ushort* __restrict__ W,
    OutT* __restrict__ C, int M, int N, int K,
    const float* __restrict__ qnw, const float* __restrict__ knw,
    const float* __restrict__ cosT, const float* __restrict__ sinT) {
  constexpr int ABYTES = 32768;           // A bytes per buffer (256 x 128B)
  constexpr int BUF = 49152;              // A + B (128 x 128B)
  __shared__ __align__(16) char lds[3 * BUF];   // 147456 B -> 1 block/CU

  // XCD-rectangular swizzle (grids are 16x16)
  const int flat = blockIdx.y * 16 + blockIdx.x;
  const int xc = flat & 7, xr = flat >> 3;
  const int n0 = ((xc & 3) * 4 + (xr & 3)) * 128;
  const int m0 = ((xc >> 2) * 8 + (xr >> 2)) * 256;
  const ushort* Wz = W + (size_t)blockIdx.z * N * K;
  OutT* Cz = C + (size_t)blockIdx.z * M * N;

  const int tid = threadIdx.x;
  const int lane = tid & 63, wid = tid >> 6;
  const int lq = lane & 15, lg = lane >> 4;
  const int wm = wid >> 1, wn = wid & 1;
  const int NT = K >> 6;                  // BK = 64
  const int wb = wid * 1024;              // wave-uniform LDS byte base per call

  const int strow = tid >> 3;             // 0..63
  const int sc8 = (((tid & 7) ^ (strow & 7)) << 3);   // element col 0..56
  const ushort* pa = A + (size_t)(m0 + strow) * K + sc8;
  const ushort* pw = Wz + (size_t)(n0 + strow) * K + sc8;

#define STG_P0(BI, KC) { \
    gload_lds16(pa + (KC), lds + (BI) * BUF + wb); \
    gload_lds16(pa + (size_t)64 * K + (KC), lds + (BI) * BUF + 8192 + wb); \
    gload_lds16(pw + (KC), lds + (BI) * BUF + ABYTES + wb); }
#define STG_P1(BI, KC) { \
    gload_lds16(pa + (size_t)128 * K + (KC), lds + (BI) * BUF + 16384 + wb); \
    gload_lds16(pa + (size_t)192 * K + (KC), lds + (BI) * BUF + 24576 + wb); \
    gload_lds16(pw + (size_t)64 * K + (KC), lds + (BI) * BUF + ABYTES + 8192 + wb); }

  f32x4 acc[4][4];
#pragma unroll
  for (int i = 0; i < 4; i++)
#pragma unroll
    for (int j = 0; j < 4; j++) acc[i][j] = (f32x4){0.f, 0.f, 0.f, 0.f};

  STG_P0(0, 0); STG_P1(0, 0);
  STG_P0(1, 64); STG_P1(1, 64);
  asm volatile("s_waitcnt vmcnt(6)" ::: "memory");
  __builtin_amdgcn_s_barrier();
  __builtin_amdgcn_sched_barrier(0);

  int b = 0, b2 = 2;                      // t%3 and (t+2)%3
  for (int t = 0; t < NT; ++t) {
    const int kc2 = (t + 2) << 6;
    const bool st = (t + 2 < NT);
    const char* bufp = lds + b * BUF;
    short8_t af[2][4], bfr[2][4];

    // all 16 fragment reads for the K-tile (two k-halves)
#pragma unroll
    for (int kk = 0; kk < 2; ++kk) {
#pragma unroll
      for (int j = 0; j < 4; ++j) {
        const int rw = wn * 64 + j * 16 + lq;
        bfr[kk][j] = *(const short8_t*)(bufp + ABYTES + rw * 128 +
                                        (((kk * 4 + lg) ^ (rw & 7)) << 4));
      }
#pragma unroll
      for (int i = 0; i < 4; ++i) {
        const int rw = wm * 64 + i * 16 + lq;
        af[kk][i] = *(const short8_t*)(bufp + rw * 128 +
                                       (((kk * 4 + lg) ^ (rw & 7)) << 4));
      }
    }
    // stage tile T+2 (6 gloads, vmcnt-counted)
    if (st) { STG_P0(b2, kc2); STG_P1(b2, kc2); }

    asm volatile("s_waitcnt lgkmcnt(0)" ::: "memory");
    __builtin_amdgcn_sched_barrier(0);
    __builtin_amdgcn_s_setprio(1);
    MFMA_KK(0);
    MFMA_KK(1);
    __builtin_amdgcn_s_setprio(0);

    // boundary: T+1 resident after this (T+2's 6 loads stay in flight)
    if (st) asm volatile("s_waitcnt vmcnt(6)" ::: "memory");
    else    asm volatile("s_waitcnt vmcnt(0)" ::: "memory");
    __builtin_amdgcn_s_barrier();
    __builtin_amdgcn_sched_barrier(0);
    b = (b == 2) ? 0 : b + 1;
    b2 = (b2 == 2) ? 0 : b2 + 1;
  }

  if constexpr (ROPE) {
    if (blockIdx.z < 2) {
      // ---- fused RoPE + per-head RMSNorm epilogue (q: z=0, k: z=1) ----
      const float* nw = (blockIdx.z == 0) ? qnw : knw;
      const float oscale = (blockIdx.z == 0) ? 0.12753102368f : 1.0f; // CL2 fold
      ushort* CT = (ushort*)lds;          // [256][136] bf16 (8B-aligned rows)
#pragma unroll
      for (int mi = 0; mi < 4; mi++)
#pragma unroll
        for (int r = 0; r < 4; r++) {
          const int row = wm * 64 + mi * 16 + lg * 4 + r;
#pragma unroll
          for (int j = 0; j < 4; j++)
            CT[row * 136 + wn * 64 + j * 16 + lq] = f2bf(acc[mi][j][r]);
        }
      __syncthreads();
      const int row = tid >> 1;
      const int i0 = (tid & 1) * 32;      // rope-pair index range
      const int m = m0 + row;
      const int s = m & (S_LEN - 1);
      float y1[32], y2[32];
      float ss = 0.f;
#pragma unroll
      for (int q8 = 0; q8 < 8; ++q8) {    // 4 rope pairs per step
        const float4 c4 = *(const float4*)&cosT[s * 64 + i0 + q8 * 4];
        const float4 s4 = *(const float4*)&sinT[s * 64 + i0 + q8 * 4];
        const short4_t x1v = *(const short4_t*)&CT[row * 136 + i0 + q8 * 4];
        const short4_t x2v = *(const short4_t*)&CT[row * 136 + 64 + i0 + q8 * 4];
#pragma unroll
        for (int e = 0; e < 4; ++e) {
          const float c = (&c4.x)[e], sn = (&s4.x)[e];
          const float x1 = bf2f((ushort)x1v[e]);
          const float x2 = bf2f((ushort)x2v[e]);
          const int k = q8 * 4 + e;
          y1[k] = x1 * c - x2 * sn;
          y2[k] = x2 * c + x1 * sn;
          ss += y1[k] * y1[k] + y2[k] * y2[k];
        }
      }
      ss += __shfl_xor(ss, 1, 64);        // pair (tid, tid^1) shares the row
      const float sc = rsqrtf(ss * (1.f / 128.f) + 1e-6f) * oscale;
      ushort* gp = (ushort*)Cz + (size_t)m * N + n0;
#pragma unroll
      for (int cu = 0; cu < 4; ++cu) {
        const float4 wa0 = *(const float4*)&nw[i0 + cu * 8];
        const float4 wa1 = *(const float4*)&nw[i0 + cu * 8 + 4];
        const float4 wb0 = *(const float4*)&nw[i0 + 64 + cu * 8];
        const float4 wb1 = *(const float4*)&nw[i0 + 64 + cu * 8 + 4];
        short8_t o1, o2;
#pragma unroll
        for (int e = 0; e < 8; ++e) {
          const int k = cu * 8 + e;
          const float w1 = (e < 4) ? (&wa0.x)[e] : (&wa1.x)[e - 4];
          const float w2 = (e < 4) ? (&wb0.x)[e] : (&wb1.x)[e - 4];
          o1[e] = (short)f2bf(y1[k] * sc * w1);
          o2[e] = (short)f2bf(y2[k] * sc * w2);
        }
        *(short8_t*)&gp[i0 + cu * 8] = o1;
        *(short8_t*)&gp[i0 + 64 + cu * 8] = o2;
      }
      return;
    }
  }

#pragma unroll
  for (int mi = 0; mi < 4; mi++) {
#pragma unroll
    for (int r = 0; r < 4; r++) {
      const int m = m0 + wm * 64 + mi * 16 + lg * 4 + r;
      OutT* cp = Cz + (size_t)m * N + n0 + wn * 64 + lq;
#pragma unroll
      for (int j = 0; j < 4; j++) store_out(cp + j * 16, acc[mi][j][r]);
    }
  }
}

// ---------------------------------------------------------------- flash attention
// ROUND-9 KERNEL VERBATIM. Grid 512, XCD-grouped heads. Block: q-tile pair
// {j, 31-j} -> uniform 33 64-key rounds. 4 waves x 16 q-rows. Double-buffered
// KV (2 x 34 KB), depth-1 prefetch. Fixed-shift exp2 softmax (q pre-scaled;
// RMSNorm bounds |s| <= 16.5 -> no max tracking); l reduced once per tile.
__global__ __launch_bounds__(256) void attn_kernel(
    const ushort* __restrict__ Q, const ushort* __restrict__ K,
    const ushort* __restrict__ V, ushort* __restrict__ O) {
  // per buffer: Ks 64x256B = 16384 | Vt half0 [128][18]u32 = 9216 | half1 9216
  __shared__ __align__(16) char LB[2][34816];

  const int bid = blockIdx.x;
  const int xcd = bid & 7;
  const int rr  = bid >> 3;              // 0..63
  const int bh  = xcd * 4 + (rr >> 4);   // 4 heads per XCD
  const int jj  = rr & 15;
  const int h = bh & 15, b = bh >> 4;
  const int tid = threadIdx.x;
  const int lane = tid & 63, w = tid >> 6;
  const int lq = lane & 15, lg = lane >> 4;

  const int vp  = tid & 15;
  const int vd0 = (tid >> 4) * 8;
  const int vc  = (vp < 8) ? ((vp >> 1) * 4 + (vp & 1))
                           : (((vp - 8) >> 1) * 4 + 2 + (vp & 1));
  const size_t bS = (size_t)b * S_LEN;

  union S8U4 { short8_t s; uint u[4]; };

#define STAGE_K64(DST, KBASE) _Pragma("unroll") for (int c = 0; c < 4; ++c) { \
    const int kr = w * 16 + c * 4 + (lane >> 4); \
    const int kc = ((lane & 15) * 16) ^ ((kr & 7) << 4); \
    gload_lds16(K + (KBASE) + (size_t)kr * HID + (kc >> 1), (DST) + w * 4096 + c * 1024); }

#define STAGE_V_LOAD(KBASE) { \
    const ushort* vs = V + (KBASE) + (size_t)(2 * vp) * HID + vd0; \
    va0.s = *(const short8_t*)vs;            vb0.s = *(const short8_t*)(vs + HID); \
    va1.s = *(const short8_t*)(vs + 32 * HID); vb1.s = *(const short8_t*)(vs + 33 * HID); }

#define STAGE_V_WRITE(VT0, VT1) \
    _Pragma("unroll") for (int j = 0; j < 4; ++j) { \
      (VT0)[(vd0 + 2 * j) * 18 + vc]     = __builtin_amdgcn_perm(vb0.u[j], va0.u[j], 0x05040100u); \
      (VT0)[(vd0 + 2 * j + 1) * 18 + vc] = __builtin_amdgcn_perm(vb0.u[j], va0.u[j], 0x07060302u); \
      (VT1)[(vd0 + 2 * j) * 18 + vc]     = __builtin_amdgcn_perm(vb1.u[j], va1.u[j], 0x05040100u); \
      (VT1)[(vd0 + 2 * j + 1) * 18 + vc] = __builtin_amdgcn_perm(vb1.u[j], va1.u[j], 0x07060302u); }

  for (int t = 0; t < 2; t++) {
    const int qt = t ? (31 - jj) : jj;
    const int q0 = qt * 64 + w * 16;
    const int qg = q0 + lq;

    const ushort* qp = Q + (bS + q0 + lq) * HID + h * HDIM + lg * 8;
    short8_t qf[4];
#pragma unroll
    for (int dc = 0; dc < 4; dc++) qf[dc] = *(const short8_t*)(qp + dc * 32);

    f32x4 o[8];
#pragma unroll
    for (int i = 0; i < 8; i++) o[i] = (f32x4){0.f, 0.f, 0.f, 0.f};
    float l_run = 0.f;
    const int NI = qt + 1;               // 64-key iterations

    {
      S8U4 va0, vb0, va1, vb1;
      uint* Vt0 = (uint*)(LB[0] + 16384);
      uint* Vt1 = (uint*)(LB[0] + 25600);
      const size_t kb0 = bS * HID + h * HDIM;
      STAGE_V_LOAD(kb0);
      STAGE_K64(LB[0], kb0);
      STAGE_V_WRITE(Vt0, Vt1);
    }
    __syncthreads();

    for (int i = 0; i < NI; ++i) {
      const int cur = i & 1;
      const int k0 = i * 64;
      const char* Ksb = LB[cur];
      const uint* Vt0 = (const uint*)(LB[cur] + 16384);
      const uint* Vt1 = (const uint*)(LB[cur] + 25600);
      char* KsbN = LB[cur ^ 1];
      uint* VtN0 = (uint*)(LB[cur ^ 1] + 16384);
      uint* VtN1 = (uint*)(LB[cur ^ 1] + 25600);
      const bool more = (i + 1 < NI);

      S8U4 va0, vb0, va1, vb1;
      if (more) {
        const size_t kbn = (bS + k0 + 64) * HID + h * HDIM;
        STAGE_V_LOAD(kbn);
        STAGE_K64(KsbN, kbn);
      }

      f32x4 st[4];
#pragma unroll
      for (int kb = 0; kb < 4; ++kb) st[kb] = (f32x4){0.f, 0.f, 0.f, 0.f};
      __builtin_amdgcn_s_setprio(1);
#pragma unroll
      for (int dc = 0; dc < 4; ++dc)
#pragma unroll
        for (int kb = 0; kb < 4; ++kb) {
          const int row = kb * 16 + lq;
          short8_t kf = *(const short8_t*)(Ksb + ((row * 256 + dc * 64 + lg * 16) ^ ((row & 7) << 4)));
          st[kb] = __builtin_amdgcn_mfma_f32_16x16x32_bf16(kf, qf[dc], st[kb], 0, 0, 0);
        }
      __builtin_amdgcn_s_setprio(0);

      if (more) STAGE_V_WRITE(VtN0, VtN1);

      float p[16]; float ps = 0.f;
#pragma unroll
      for (int kb = 0; kb < 4; ++kb)
#pragma unroll
        for (int r = 0; r < 4; ++r) {
          const int kk = k0 + kb * 16 + lg * 4 + r;
          const float e = exp2f((kk <= qg) ? st[kb][r] : -1e30f);
          p[kb * 4 + r] = e;
          ps += e;
        }
      l_run += ps;

      uint pk[8];
#pragma unroll
      for (int j = 0; j < 8; ++j)
        asm("v_cvt_pk_bf16_f32 %0, %1, %2" : "=v"(pk[j]) : "v"(p[2 * j]), "v"(p[2 * j + 1]));
      union { uint u[4]; short8_t s; } P0, P1;
      P0.u[0] = pk[0]; P0.u[1] = pk[1]; P0.u[2] = pk[2]; P0.u[3] = pk[3];
      P1.u[0] = pk[4]; P1.u[1] = pk[5]; P1.u[2] = pk[6]; P1.u[3] = pk[7];

      __builtin_amdgcn_s_setprio(1);
#pragma unroll
      for (int nt = 0; nt < 8; nt++) {
        const uint* vq0 = &Vt0[(nt * 16 + lq) * 18 + lg * 4];
        const uint* vq1 = &Vt1[(nt * 16 + lq) * 18 + lg * 4];
        uint2 a0 = *(const uint2*)vq0, a1 = *(const uint2*)(vq0 + 2);
        uint2 b0v = *(const uint2*)vq1, b1v = *(const uint2*)(vq1 + 2);
        union { uint u[4]; short8_t s; } V0, V1;
        V0.u[0] = a0.x; V0.u[1] = a0.y; V0.u[2] = a1.x; V0.u[3] = a1.y;
        V1.u[0] = b0v.x; V1.u[1] = b0v.y; V1.u[2] = b1v.x; V1.u[3] = b1v.y;
        o[nt] = __builtin_amdgcn_mfma_f32_16x16x32_bf16(P0.s, V0.s, o[nt], 0, 0, 0);
        o[nt] = __builtin_amdgcn_mfma_f32_16x16x32_bf16(P1.s, V1.s, o[nt], 0, 0, 0);
      }
      __builtin_amdgcn_s_setprio(0);

      __syncthreads();
    }

    float lf = l_run;
    lf += __shfl_xor(lf, 16, 64);
    lf += __shfl_xor(lf, 32, 64);
    const float invl = 1.f / lf;          // diagonal key always live -> lf > 0
#pragma unroll
    for (int r = 0; r < 4; r++) {
      const float iv = __shfl(invl, lg * 4 + r, 64);
      ushort* op = O + (bS + q0 + lg * 4 + r) * HID + h * HDIM + lq;
#pragma unroll
      for (int nt = 0; nt < 8; nt++) op[nt * 16] = f2bf(o[nt][r] * iv);
    }
    __syncthreads();                      // protect LB[0] reuse by next tile
  }
}

// ---------------------------------------------------------------- launcher
extern "C" void kernel_launch(void* const* d_in, const int* in_sizes, int n_in,
                              void* d_out, int out_size, void* d_ws, size_t ws_size,
                              hipStream_t stream) {
  const float* x   = (const float*)d_in[0];
  const float* wq  = (const float*)d_in[1];
  const float* wk  = (const float*)d_in[2];
  const float* wv  = (const float*)d_in[3];
  const float* wo  = (const float*)d_in[4];
  const float* qnw = (const float*)d_in[5];
  const float* knw = (const float*)d_in[6];
  float* out = (float*)d_out;
  char* ws = (char*)d_ws;

  const size_t NELEM = (size_t)MROWS * HID;       // 8388608
  const size_t WELEM = (size_t)HID * HID;         // 4194304

  ushort* xb    = (ushort*)(ws);                          // 16777216 B
  ushort* wqkvb = (ushort*)(ws + 16777216);               // 25165824 B
  ushort* wob   = (ushort*)(ws + 41943040);               //  8388608 B
  ushort* qkv   = (ushort*)(ws + 50331648);               // 50331648 B (q,k,v)
  float*  cosT  = (float*)(ws + 100663296);               //   524288 B
  float*  sinT  = (float*)(ws + 101187584);               //   524288 B
  ushort* attnb = xb;                                     // alias (xb dead after QKV)

  cast_all_kernel<<<2048, 256, 0, stream>>>(x, wq, wk, wv, wo, xb, wqkvb, wob,
                                            cosT, sinT);

  // QKV with fused rope+rmsnorm epilogue, XCD-rectangular swizzle
  gemm_pipe_kernel<ushort, true><<<dim3(16, 16, 3), 512, 0, stream>>>(
      xb, wqkvb, qkv, MROWS, HID, HID, qnw, knw, cosT, sinT);

  // attention: 512 blocks x 256 threads, XCD-grouped heads, 64-key rounds
  attn_kernel<<<512, 256, 0, stream>>>(qkv, qkv + NELEM, qkv + 2 * NELEM, attnb);

  // out = attn @ wo^T (fp32 out): swizzled
  gemm_pipe_kernel<float, false><<<dim3(16, 16, 1), 512, 0, stream>>>(
      attnb, wob, out, MROWS, HID, HID, nullptr, nullptr, nullptr, nullptr);
}